// Round 4
// baseline (122.148 us; speedup 1.0000x reference)
//
#include <hip/hip_runtime.h>
#include <hip/hip_bf16.h>

#define BSZ 8192
#define BTZ 8192
#define DD 64
#define NC 10
#define SHIFT2 20.0f   // log2-domain shift
#define LN2 0.69314718055994531f
#define LOG2E 1.44269504088896341f

typedef __attribute__((ext_vector_type(8))) short bf16x8;
typedef __attribute__((ext_vector_type(4))) float f32x4;

#if defined(__has_builtin)
#if __has_builtin(__builtin_amdgcn_exp2f)
#define EXP2(x) __builtin_amdgcn_exp2f(x)
#else
#define EXP2(x) exp2f(x)
#endif
#else
#define EXP2(x) exp2f(x)
#endif

__device__ __forceinline__ unsigned short f2bf_rne(float f) {
    unsigned int u = __float_as_uint(f);
    u += 0x7FFFu + ((u >> 16) & 1u);
    return (unsigned short)(u >> 16);
}

// Kernel AB (fused): blocks 0..511 convert f32->bf16 (src pre-scaled by log2e).
// Blocks 512..543: per-tgt top2/conf/cls, self-computed label histogram
// (register compare-accumulate, no atomics), confident-column compaction via
// global cursor, cc partials, cls8, S-zero.
__global__ __launch_bounds__(256) void kAB(
    const float4* __restrict__ src4, const float4* __restrict__ tgt4,
    const int* __restrict__ labels, const float* __restrict__ logits,
    ushort4* __restrict__ srcb, ushort4* __restrict__ tgtb,
    float* __restrict__ S, float* __restrict__ counts,
    float* __restrict__ cc_part, unsigned char* __restrict__ cls8,
    float* __restrict__ cbias_c, int* __restrict__ cidx,
    int* __restrict__ gcursor)
{
    int t = threadIdx.x;
    if (blockIdx.x < 512) {
        int tid = blockIdx.x * 256 + t;   // 131072 threads = 8192*64/4
        float4 s = src4[tid];
        ushort4 os;
        os.x = f2bf_rne(s.x * LOG2E); os.y = f2bf_rne(s.y * LOG2E);
        os.z = f2bf_rne(s.z * LOG2E); os.w = f2bf_rne(s.w * LOG2E);
        srcb[tid] = os;
        float4 v = tgt4[tid];
        ushort4 ot; ot.x = f2bf_rne(v.x); ot.y = f2bf_rne(v.y);
        ot.z = f2bf_rne(v.z); ot.w = f2bf_rne(v.w);
        tgtb[tid] = ot;
        return;
    }
    __shared__ float lcnt[NC];
    __shared__ float hist[NC];
    __shared__ float hred[4][NC];
    __shared__ int lpos;
    __shared__ int lbase;
    int b = blockIdx.x - 512;
    int i = b * 256 + t;
    int w = t >> 6, lane = t & 63;

    // self-histogram of all src labels (each block redundantly; cheap)
    float c10[NC];
    #pragma unroll
    for (int c = 0; c < NC; ++c) c10[c] = 0.0f;
    for (int k = 0; k < 32; ++k) {
        int lab = labels[t + 256 * k];
        #pragma unroll
        for (int c = 0; c < NC; ++c) c10[c] += (lab == c) ? 1.0f : 0.0f;
    }
    #pragma unroll
    for (int c = 0; c < NC; ++c) {
        float v = c10[c];
        #pragma unroll
        for (int m = 1; m < 64; m <<= 1) v += __shfl_xor(v, m);
        if (lane == 0) hred[w][c] = v;
    }
    if (t == 0) lpos = 0;
    if (t < NC) hist[t] = 0.0f;
    __syncthreads();
    if (t < NC) lcnt[t] = hred[0][t] + hred[1][t] + hred[2][t] + hred[3][t];
    __syncthreads();
    if (b == 0 && t < NC) counts[t] = lcnt[t];

    float m1 = -3.0e38f, m2 = -3.0e38f; int cls = 0;
    #pragma unroll
    for (int c = 0; c < NC; ++c) {
        float v = logits[i * NC + c];
        if (v > m1) { m2 = m1; m1 = v; cls = c; }
        else if (v > m2) { m2 = v; }
    }
    bool conf = (m1 - m2) >= 0.1f;
    float cnt = lcnt[cls];
    bool live = conf && (cnt > 0.0f);
    cls8[i] = live ? (unsigned char)cls : (unsigned char)255;
    S[i] = 0.0f;
    if (conf) atomicAdd(&hist[cls], 1.0f);
    int myp = 0;
    if (live) myp = atomicAdd(&lpos, 1);
    __syncthreads();
    if (t < NC) cc_part[b * NC + t] = hist[t];
    if (t == 0) lbase = atomicAdd(gcursor, lpos);
    __syncthreads();
    if (live) {
        cidx[lbase + myp] = i;
        cbias_c[lbase + myp] = log2f(cnt) - SHIFT2;
    }
}

// Kernel C: blocks 0..2047: fused bf16 MFMA GEMM over COMPACTED columns +
// exp2 row-sum (no term1 in inner loop). Blocks 2048..2111: SC/T per-class
// feature sums (f32) via register compare-accumulate + global atomics.
__global__ __launch_bounds__(256) void kC(
    const unsigned short* __restrict__ srcb, const unsigned short* __restrict__ tgtb,
    const float* __restrict__ cbias_c, const int* __restrict__ cidx,
    const int* __restrict__ gcursor, float* __restrict__ S,
    const float* __restrict__ srcf, const float* __restrict__ tgtf,
    const int* __restrict__ labels, const unsigned char* __restrict__ cls8,
    float* __restrict__ SC, float* __restrict__ T)
{
    int t = threadIdx.x;
    if (blockIdx.x >= 2048) {
        int bb = blockIdx.x - 2048;       // 0..63
        bool isT = bb >= 32;
        int rb = (bb & 31) * 256;
        const float* F = isT ? tgtf : srcf;
        int w = t >> 6, lane = t & 63;
        float acc[NC];
        #pragma unroll
        for (int c = 0; c < NC; ++c) acc[c] = 0.0f;
        int row0 = rb + w * 64;
        for (int r = 0; r < 64; ++r) {
            int row = row0 + r;
            int lab = isT ? (int)cls8[row] : labels[row];
            float f = F[row * DD + lane];
            #pragma unroll
            for (int c = 0; c < NC; ++c) acc[c] += (lab == c) ? f : 0.0f;
        }
        float* OUT = isT ? T : SC;
        #pragma unroll
        for (int c = 0; c < NC; ++c) atomicAdd(&OUT[c * DD + lane], acc[c]);
        return;
    }

    __shared__ float lds[4][64];
    int w = t >> 6;
    int lane = t & 63;
    int l15 = lane & 15;
    int quad = lane >> 4;
    int colchunk = blockIdx.x & 15;
    int rowg = blockIdx.x >> 4;
    int row_base = rowg * 64;
    int Pn = *gcursor;
    if (colchunk * 512 >= Pn) return;   // uniform whole-block early exit

    bf16x8 a[4][2];
    #pragma unroll
    for (int mb = 0; mb < 4; ++mb) {
        const bf16x8* p = (const bf16x8*)(srcb + (size_t)(row_base + mb * 16 + l15) * DD + quad * 8);
        a[mb][0] = p[0];   // k = quad*8 + j
        a[mb][1] = p[4];   // k = 32 + quad*8 + j
    }

    float rs[4][4];
    #pragma unroll
    for (int mb = 0; mb < 4; ++mb)
        #pragma unroll
        for (int r = 0; r < 4; ++r) rs[mb][r] = 0.0f;

    int col0 = colchunk * 512 + w * 128;
    #pragma unroll 2
    for (int ct = 0; ct < 8; ++ct) {
        int cb = col0 + ct * 16;
        int cc = cb + l15;                 // always < 8192: in-bounds read
        bool ok = cc < Pn;
        int col = ok ? cidx[cc] : 0;
        float cb2 = ok ? cbias_c[cc] : -1.0e30f;
        const bf16x8* q = (const bf16x8*)(tgtb + (size_t)col * DD + quad * 8);
        bf16x8 b0 = q[0];
        bf16x8 b1 = q[4];
        #pragma unroll
        for (int mb = 0; mb < 4; ++mb) {
            f32x4 acc = {cb2, cb2, cb2, cb2};
            acc = __builtin_amdgcn_mfma_f32_16x16x32_bf16(a[mb][0], b0, acc, 0, 0, 0);
            acc = __builtin_amdgcn_mfma_f32_16x16x32_bf16(a[mb][1], b1, acc, 0, 0, 0);
            #pragma unroll
            for (int r = 0; r < 4; ++r)
                rs[mb][r] += EXP2(acc[r]);
        }
    }

    #pragma unroll
    for (int mb = 0; mb < 4; ++mb) {
        #pragma unroll
        for (int r = 0; r < 4; ++r) {
            float v = rs[mb][r];
            v += __shfl_xor(v, 1);
            v += __shfl_xor(v, 2);
            v += __shfl_xor(v, 4);
            v += __shfl_xor(v, 8);
            if (l15 == 0) lds[w][mb * 16 + quad * 4 + r] = v;
        }
    }
    __syncthreads();
    if (t < 64)
        atomicAdd(&S[row_base + t], lds[0][t] + lds[1][t] + lds[2][t] + lds[3][t]);
}

// Kernel D: 32 blocks; termL partials -> device atomic; last block does the
// finale (term1 = sum SC*T, P, output).
__global__ __launch_bounds__(256) void kD(
    const float* __restrict__ S, const int* __restrict__ labels,
    const float* __restrict__ counts, const float* __restrict__ cc_part,
    const float* __restrict__ SC, const float* __restrict__ T,
    float* __restrict__ gACC, int* __restrict__ gcnt,
    float* __restrict__ out)
{
    __shared__ float cc[NC];
    __shared__ float redL[4], red1[4], redP[4];
    __shared__ int isLast;
    int t = threadIdx.x;
    int w = t >> 6, lane = t & 63;
    if (t < NC) {
        float s = 0.0f;
        #pragma unroll
        for (int k = 0; k < 32; ++k) s += cc_part[k * NC + t];
        cc[t] = s;
    }
    __syncthreads();
    int j = blockIdx.x * 256 + t;
    float L = (log2f(S[j]) + SHIFT2) * LN2;
    float tl = cc[labels[j]] * L;
    #pragma unroll
    for (int m = 1; m < 64; m <<= 1) tl += __shfl_xor(tl, m);
    if (lane == 0) redL[w] = tl;
    __syncthreads();
    if (t == 0) {
        float v = redL[0] + redL[1] + redL[2] + redL[3];
        atomicAdd(&gACC[0], v);
        __threadfence();
        int old = atomicAdd(gcnt, 1);
        isLast = (old == 31) ? 1 : 0;
    }
    __syncthreads();
    if (!isLast) return;

    // finale
    float t1 = 0.0f;
    for (int o = t; o < NC * DD; o += 256) t1 += SC[o] * T[o];
    float Pp = (t < NC) ? counts[t] * cc[t] : 0.0f;
    #pragma unroll
    for (int m = 1; m < 64; m <<= 1) {
        t1 += __shfl_xor(t1, m);
        Pp += __shfl_xor(Pp, m);
    }
    if (lane == 0) { red1[w] = t1; redP[w] = Pp; }
    __syncthreads();
    if (t == 0) {
        float term1 = red1[0] + red1[1] + red1[2] + red1[3];
        float P = redP[0] + redP[1] + redP[2] + redP[3];
        float termL = atomicAdd(&gACC[0], 0.0f);   // coherent read of final sum
        out[0] = (term1 - termL) / (-(float)BSZ * P);
    }
}

extern "C" void kernel_launch(void* const* d_in, const int* in_sizes, int n_in,
                              void* d_out, int out_size, void* d_ws, size_t ws_size,
                              hipStream_t stream) {
    const float* src    = (const float*)d_in[0];
    const int*   labels = (const int*)d_in[1];
    const float* tgt    = (const float*)d_in[2];
    const float* logits = (const float*)d_in[3];

    char* ws = (char*)d_ws;
    float* S        = (float*)(ws + 0);         // 32768 B (zeroed by kAB)
    int*   gcursor  = (int*)(ws + 32768);       // 4 B   (memset)
    int*   gcnt     = (int*)(ws + 32772);       // 4 B   (memset)
    float* gACC     = (float*)(ws + 32776);     // 8 B   (memset)
    float* counts   = (float*)(ws + 32784);     // 40 B  (written by kAB b==0)
    float* cc_part  = (float*)(ws + 32832);     // 1280 B (written by kAB)
    float* SC       = (float*)(ws + 34112);     // 2560 B (memset; atomics in kC)
    float* T        = (float*)(ws + 36672);     // 2560 B (memset; atomics in kC)
    float* cbias_c  = (float*)(ws + 40960);     // 32768 B
    int*   cidx     = (int*)(ws + 73728);       // 32768 B
    unsigned char* cls8 = (unsigned char*)(ws + 106496);   // 8192 B
    unsigned short* srcb = (unsigned short*)(ws + 114688);           // 1 MiB
    unsigned short* tgtb = (unsigned short*)(ws + 114688 + 1048576); // 1 MiB

    hipMemsetAsync(ws + 32768, 0, 8192, stream);  // cursor/cnt/gACC/SC/T etc.
    kAB<<<544, 256, 0, stream>>>((const float4*)src, (const float4*)tgt, labels,
                                 logits, (ushort4*)srcb, (ushort4*)tgtb,
                                 S, counts, cc_part, cls8, cbias_c, cidx, gcursor);
    kC<<<2112, 256, 0, stream>>>(srcb, tgtb, cbias_c, cidx, gcursor, S,
                                 src, tgt, labels, cls8, SC, T);
    kD<<<32, 256, 0, stream>>>(S, labels, counts, cc_part, SC, T,
                               gACC, gcnt, (float*)d_out);
}